// Round 2
// 265.887 us; speedup vs baseline: 1.3561x; 1.3561x over previous
//
#include <hip/hip_runtime.h>
#include <math.h>

// Problem constants
#define T_TOKENS 16384
#define HID      2048
#define NE       64     // experts
#define TOPK     8
// Tiling
#define TM   32         // tokens per block -> grid 512 = 2 blocks/CU
#define BK   64         // k-chunk
#define ASTR 68         // f32 row stride: 272 B (16B aligned); 68 dw == 4 mod 32 ->
                        // MFMA frag reads hit every bank exactly 2x = conflict-free
#define BSTR 68
#define NCH  (HID / BK) // 32 chunks

typedef double dbl4 __attribute__((ext_vector_type(4)));

__global__ __launch_bounds__(256, 2) void router_kernel(
    const float* __restrict__ hidden,   // [T_TOKENS, HID] f32
    const float* __restrict__ weight,   // [NE, HID] f32
    float* __restrict__ out_logits,     // [T_TOKENS, NE]
    float* __restrict__ out_vals,       // [T_TOKENS, TOPK]
    float* __restrict__ out_idxf)       // [T_TOKENS, TOPK] (indices as float)
{
    // Double-buffered f32 staging: As[TM][ASTR] + Bs[NE][BSTR] per buffer.
    // 2*(32*68 + 64*68)*4 = 52224 B -> 2 blocks/CU at 160 KiB.
    // Epilogue aliases lg[TM][65] f64 (16640 B) over the front.
    __shared__ __align__(16) float smem[2 * (TM * ASTR + NE * BSTR)];
    double (*lg)[NE + 1] = reinterpret_cast<double(*)[NE + 1]>(smem);

    const int tid  = threadIdx.x;
    const int tok0 = blockIdx.x * TM;
    const int lane = tid & 63;
    const int wave = tid >> 6;   // 0..3
    const int tw   = wave & 1;   // token sub-tile (16 tokens)
    const int eh   = wave >> 1;  // expert half (32 experts = 2 MFMA tiles)

    // Assumed INPUT fragment layout for v_mfma_f64_16x16x4_f64 (standard for
    // all 16x16 shapes): operand element of lane l = M[l&15][l>>4].
    const int fr = lane & 15;
    const int fk = lane >> 4;

    // ---- runtime D-layout probe (2 MFMAs) ----
    // pr: A[m][k]=m, B[k][n]=0.25 -> D[m][n] = sum_k m*0.25 = m exactly.
    //     So each acc slot's probe value == the TOKEN index (as fed) it holds.
    // pc: A=0.25, B[k][n]=n -> slot value == the EXPERT index (as fed).
    // Robust to any bijective D mapping, operand-role swap, and row/col
    // permutations inside the input fragments.
    int rowmap[4], colmap[4];
    {
        const dbl4 z = {0.0, 0.0, 0.0, 0.0};
        const dbl4 pr = __builtin_amdgcn_mfma_f64_16x16x4f64((double)fr, 0.25, z, 0, 0, 0);
        const dbl4 pc = __builtin_amdgcn_mfma_f64_16x16x4f64(0.25, (double)fr, z, 0, 0, 0);
        #pragma unroll
        for (int i = 0; i < 4; ++i) {
            rowmap[i] = (int)pr[i];
            colmap[i] = (int)pc[i];
        }
    }

    // Staging maps (fully coalesced 256B segments)
    const int ar = tid >> 3;          // A row 0..31, 8 f32/thread
    const int ac = (tid & 7) * 8;
    const int be = tid >> 2;          // B row 0..63, 16 f32/thread
    const int bc = (tid & 3) * 16;

    const float* aG = hidden + (size_t)(tok0 + ar) * HID + ac;
    const float* bG = weight + (size_t)be * HID + bc;

    const int BUFSZ = TM * ASTR + NE * BSTR;   // floats per buffer

    dbl4 acc0 = {0.0, 0.0, 0.0, 0.0};   // experts eh*32 + colmap
    dbl4 acc1 = {0.0, 0.0, 0.0, 0.0};   // experts eh*32 + 16 + colmap

    // ---- stage chunk 0 into buffer 0 ----
    {
        float* A0 = smem;
        float* B0 = smem + TM * ASTR;
        const float4 a0 = *(const float4*)(aG);
        const float4 a1 = *(const float4*)(aG + 4);
        *(float4*)&A0[ar * ASTR + ac]     = a0;
        *(float4*)&A0[ar * ASTR + ac + 4] = a1;
        #pragma unroll
        for (int q = 0; q < 4; ++q) {
            const float4 w = *(const float4*)(bG + 4 * q);
            *(float4*)&B0[be * BSTR + bc + 4 * q] = w;
        }
    }
    __syncthreads();

    // Frag read offsets (element units) within a buffer
    const int aOff = (tw * 16 + fr) * ASTR + fk;
    const int bOff = (eh * 32 + fr) * BSTR + fk;

    for (int c = 0; c < NCH; ++c) {
        const int cur = c & 1;
        const float* As = smem + cur * BUFSZ;
        const float* Bs = As + TM * ASTR;

        // T14 async-stage split: issue next chunk's global loads FIRST so
        // HBM latency hides under the MFMA phase; LDS-write them after.
        float4 a0, a1, w0, w1, w2, w3;
        if (c + 1 < NCH) {
            const int off = (c + 1) * BK;
            a0 = *(const float4*)(aG + off);
            a1 = *(const float4*)(aG + off + 4);
            w0 = *(const float4*)(bG + off);
            w1 = *(const float4*)(bG + off + 4);
            w2 = *(const float4*)(bG + off + 8);
            w3 = *(const float4*)(bG + off + 12);
        }

        // ---- compute: 16 k-steps, 2 f64 MFMAs each ----
        const float* aP = As + aOff;
        const float* bP = Bs + bOff;
        #pragma unroll
        for (int s = 0; s < BK / 4; ++s) {
            const double av = (double)aP[4 * s];               // A[m][4s+fk]
            const double b0 = (double)bP[4 * s];               // W[e0+fr][4s+fk]
            const double b1 = (double)bP[16 * BSTR + 4 * s];   // W[e0+16+fr][..]
            acc0 = __builtin_amdgcn_mfma_f64_16x16x4f64(av, b0, acc0, 0, 0, 0);
            acc1 = __builtin_amdgcn_mfma_f64_16x16x4f64(av, b1, acc1, 0, 0, 0);
        }

        // ---- write next chunk into the other buffer ----
        if (c + 1 < NCH) {
            float* Ad = smem + (cur ^ 1) * BUFSZ;
            float* Bd = Ad + TM * ASTR;
            *(float4*)&Ad[ar * ASTR + ac]      = a0;
            *(float4*)&Ad[ar * ASTR + ac + 4]  = a1;
            *(float4*)&Bd[be * BSTR + bc]      = w0;
            *(float4*)&Bd[be * BSTR + bc + 4]  = w1;
            *(float4*)&Bd[be * BSTR + bc + 8]  = w2;
            *(float4*)&Bd[be * BSTR + bc + 12] = w3;
        }
        // One barrier per chunk: covers "stage c+1 done before compute c+1"
        // AND "compute c done before stage c+2 overwrites this buffer".
        __syncthreads();
    }

    // ---- epilogue: write logits + stash f64 logits in LDS (aliases staging;
    //      the k-loop's final barrier guarantees all LDS reads are done;
    //      last compute read buffer 1, lg aliases buffer 0) ----
    #pragma unroll
    for (int i = 0; i < 4; ++i) {
        const int trow = tw * 16 + rowmap[i];
        const int tok  = tok0 + trow;
        const int e0   = eh * 32 + colmap[i];
        const int e1   = e0 + 16;
        out_logits[(size_t)tok * NE + e0] = (float)acc0[i];
        out_logits[(size_t)tok * NE + e1] = (float)acc1[i];
        lg[trow][e0] = acc0[i];
        lg[trow][e1] = acc1[i];
    }
    __syncthreads();

    // ---- per-token top-8 + renormalized softmax (unchanged, verified) ----
    for (int tt = wave; tt < TM; tt += 4) {
        double cur = lg[tt][lane];
        double first = 0.0, s = 0.0, myv = 0.0;
        int myi = 0;
        #pragma unroll
        for (int i = 0; i < TOPK; ++i) {
            double mv = cur;
            int    mi = lane;
            #pragma unroll
            for (int off = 32; off; off >>= 1) {
                const double ov = __shfl_xor(mv, off);
                const int    oi = __shfl_xor(mi, off);
                if (ov > mv || (ov == mv && oi < mi)) { mv = ov; mi = oi; }
            }
            if (i == 0) first = mv;
            const double e = exp(mv - first);
            s += e;
            if (lane == i)  { myv = e; myi = mi; }
            if (lane == mi) cur = -INFINITY;   // remove winner
        }
        if (lane < TOPK) {
            const int tok = tok0 + tt;
            out_vals[(size_t)tok * TOPK + lane] = (float)(myv / s);
            out_idxf[(size_t)tok * TOPK + lane] = (float)myi;
        }
    }
}

extern "C" void kernel_launch(void* const* d_in, const int* in_sizes, int n_in,
                              void* d_out, int out_size, void* d_ws, size_t ws_size,
                              hipStream_t stream) {
    const float* hidden = (const float*)d_in[0];   // [16384, 2048] f32
    const float* weight = (const float*)d_in[1];   // [64, 2048] f32

    float* out        = (float*)d_out;
    float* out_logits = out;
    float* out_vals   = out + (size_t)T_TOKENS * NE;
    float* out_idxf   = out + (size_t)T_TOKENS * NE + (size_t)T_TOKENS * TOPK;

    dim3 grid(T_TOKENS / TM);
    dim3 block(256);
    hipLaunchKernelGGL(router_kernel, grid, block, 0, stream,
                       hidden, weight, out_logits, out_vals, out_idxf);
}

// Round 3
// 235.307 us; speedup vs baseline: 1.5324x; 1.1300x over previous
//
#include <hip/hip_runtime.h>
#include <math.h>

// Problem constants
#define T_TOKENS 16384
#define HID      2048
#define NE       64
#define TOPK     8
// Tiling
#define TM       32              // tokens per block -> grid 512 = 2 blocks/CU
#define BK       128             // k-chunk
#define NCH      (HID / BK)      // 16
// LDS geometry (bytes). Row = 136 bf16 = BK + 8 pad = 272 B = 68 dw == 4 mod 32:
// 16-row frag reads hit each bank exactly 2x (free); staged b128 writes are
// bank-balanced (8 accesses/bank, even). No swizzle needed.
#define RSTR     272
#define A_SPL    8704            // 32 * 272   (one A split plane)
#define B_SPL    17408           // 64 * 272   (one B split plane)
#define B_OFF    26112           // 3 * A_SPL
#define LDS_BYTES 78336          // B_OFF + 3*B_SPL -> 2 blocks/CU (156.7 KB)

typedef float  f32x4  __attribute__((ext_vector_type(4)));
typedef short  short8 __attribute__((ext_vector_type(8)));

#define MFMA16(A, B, C) __builtin_amdgcn_mfma_f32_16x16x32_bf16((A), (B), (C), 0, 0, 0)

// f32 <-> bf16 in pure bit ops (RNE), cheaper than cvt intrinsics round-trip
static __device__ __forceinline__ unsigned short f2bf(float x) {
    unsigned u = __builtin_bit_cast(unsigned, x);
    return (unsigned short)((u + 0x7FFFu + ((u >> 16) & 1u)) >> 16);
}
static __device__ __forceinline__ float bf2f(unsigned short h) {
    unsigned u = ((unsigned)h) << 16;
    return __builtin_bit_cast(float, u);
}
// 3-term bf16 split: x ~= h0 + h1 + h2, |x - sum| <= 2^-27 |x|
static __device__ __forceinline__ void split1(float x, unsigned short& h0,
                                              unsigned short& h1, unsigned short& h2) {
    h0 = f2bf(x); float r = x - bf2f(h0);
    h1 = f2bf(r); r = r - bf2f(h1);
    h2 = f2bf(r);
}
// Split one float4 into elements [B..B+3] of three short8 frags (const idx only)
#define SPLIT4(V, B, S0, S1, S2) do {                                             \
    unsigned short h0_, h1_, h2_;                                                 \
    split1((V).x, h0_, h1_, h2_); (S0)[(B)+0]=(short)h0_; (S1)[(B)+0]=(short)h1_; (S2)[(B)+0]=(short)h2_; \
    split1((V).y, h0_, h1_, h2_); (S0)[(B)+1]=(short)h0_; (S1)[(B)+1]=(short)h1_; (S2)[(B)+1]=(short)h2_; \
    split1((V).z, h0_, h1_, h2_); (S0)[(B)+2]=(short)h0_; (S1)[(B)+2]=(short)h1_; (S2)[(B)+2]=(short)h2_; \
    split1((V).w, h0_, h1_, h2_); (S0)[(B)+3]=(short)h0_; (S1)[(B)+3]=(short)h1_; (S2)[(B)+3]=(short)h2_; \
} while (0)

__global__ __launch_bounds__(256, 2) void router_kernel(
    const float* __restrict__ hidden,   // [T_TOKENS, HID] f32
    const float* __restrict__ weight,   // [NE, HID] f32
    float* __restrict__ out_logits,     // [T_TOKENS, NE]
    float* __restrict__ out_vals,       // [T_TOKENS, TOPK]
    float* __restrict__ out_idxf)       // [T_TOKENS, TOPK] (indices as float)
{
    __shared__ __align__(16) char smem[LDS_BYTES];
    double (*lg)[NE + 1] = reinterpret_cast<double(*)[NE + 1]>(smem);

    const int tid  = threadIdx.x;
    const int tok0 = blockIdx.x * TM;
    const int lane = tid & 63;
    const int wave = tid >> 6;   // 0..3
    const int tw   = wave & 1;   // token sub-tile (16 tokens)
    const int eh   = wave >> 1;  // expert half (2 x 16-expert MFMA tiles)

    const int fr = lane & 15;    // frag row/col
    const int fk = lane >> 4;    // frag k-octet (0..3)

    // ---- runtime D-layout probe (self-correcting for any bijective D map /
    //      operand-role swap; same trick that fixed the f64 kernel) ----
    int rowmap[4], colmap[4];
    {
        const unsigned short mb = f2bf((float)fr);     // 0..15 exact in bf16
        const unsigned short ob = f2bf(0.03125f);      // 1/32 exact
        short8 vm, vo;
        #pragma unroll
        for (int j = 0; j < 8; ++j) { vm[j] = (short)mb; vo[j] = (short)ob; }
        const f32x4 z = {0.f, 0.f, 0.f, 0.f};
        const f32x4 pr = MFMA16(vm, vo, z);  // slot value == token row it holds
        const f32x4 pc = MFMA16(vo, vm, z);  // slot value == expert col it holds
        #pragma unroll
        for (int i = 0; i < 4; ++i) {
            rowmap[i] = (int)(pr[i] + 0.5f);
            colmap[i] = (int)(pc[i] + 0.5f);
        }
    }

    // Staging maps (coalesced 256-512B segments per row group)
    const int ar    = tid >> 3;          // A row 0..31, 16 f32/thread
    const int ac16  = (tid & 7) * 16;
    const int be    = tid >> 2;          // B row 0..63, 32 f32/thread
    const int bslot = tid & 3;           // 32-elem (64 B) column slot

    const float* aG = hidden + (size_t)(tok0 + ar) * HID + ac16;
    const float* bG = weight + (size_t)be * HID + bslot * 32;
    char* const  aW = smem + ar * RSTR + 2 * ac16;
    char* const  bW = smem + B_OFF + be * RSTR + (bslot << 6);

    // Frag read bases (bytes)
    const int aBase = (tw * 16 + fr) * RSTR + fk * 16;
    const int bBase = B_OFF + (eh * 32 + fr) * RSTR + fk * 16;

    const f32x4 z4 = {0.f, 0.f, 0.f, 0.f};
    f32x4 acch0 = z4, acch1 = z4;        // a0*b0 (dumped to f64 each chunk)
    f32x4 accl0 = z4, accl1 = z4;        // 5 correction terms (f32 whole K)
    double accd0[4] = {0, 0, 0, 0}, accd1[4] = {0, 0, 0, 0};

    float4 pa[4], pb[8];

#define STAGE() do {                                                              \
    short8 sa0a, sa0b, sa1a, sa1b, sa2a, sa2b;                                    \
    SPLIT4(pa[0], 0, sa0a, sa1a, sa2a); SPLIT4(pa[1], 4, sa0a, sa1a, sa2a);       \
    SPLIT4(pa[2], 0, sa0b, sa1b, sa2b); SPLIT4(pa[3], 4, sa0b, sa1b, sa2b);       \
    *(short8*)(aW            ) = sa0a;  *(short8*)(aW             + 16) = sa0b;   \
    *(short8*)(aW +   A_SPL  ) = sa1a;  *(short8*)(aW +   A_SPL   + 16) = sa1b;   \
    *(short8*)(aW + 2*A_SPL  ) = sa2a;  *(short8*)(aW + 2*A_SPL   + 16) = sa2b;   \
    short8 sb0[4], sb1[4], sb2[4];                                                \
    SPLIT4(pb[0], 0, sb0[0], sb1[0], sb2[0]); SPLIT4(pb[1], 4, sb0[0], sb1[0], sb2[0]); \
    SPLIT4(pb[2], 0, sb0[1], sb1[1], sb2[1]); SPLIT4(pb[3], 4, sb0[1], sb1[1], sb2[1]); \
    SPLIT4(pb[4], 0, sb0[2], sb1[2], sb2[2]); SPLIT4(pb[5], 4, sb0[2], sb1[2], sb2[2]); \
    SPLIT4(pb[6], 0, sb0[3], sb1[3], sb2[3]); SPLIT4(pb[7], 4, sb0[3], sb1[3], sb2[3]); \
    _Pragma("unroll")                                                             \
    for (int q_ = 0; q_ < 4; ++q_) {                                              \
        *(short8*)(bW             + 16 * q_) = sb0[q_];                           \
        *(short8*)(bW +   B_SPL   + 16 * q_) = sb1[q_];                           \
        *(short8*)(bW + 2*B_SPL   + 16 * q_) = sb2[q_];                           \
    }                                                                             \
} while (0)

    // ---- prologue: stage chunk 0 ----
    #pragma unroll
    for (int q = 0; q < 4; ++q) pa[q] = *(const float4*)(aG + 4 * q);
    #pragma unroll
    for (int q = 0; q < 8; ++q) pb[q] = *(const float4*)(bG + 4 * q);
    STAGE();
    __syncthreads();

    for (int c = 0; c < NCH; ++c) {
        // T14: issue next chunk's global loads first; latency hides under MFMA
        if (c + 1 < NCH) {
            const int off = (c + 1) * BK;
            #pragma unroll
            for (int q = 0; q < 4; ++q) pa[q] = *(const float4*)(aG + off + 4 * q);
            #pragma unroll
            for (int q = 0; q < 8; ++q) pb[q] = *(const float4*)(bG + off + 4 * q);
        }

        // ---- compute: 4 k-steps (K=32 each), 12 bf16 MFMAs per step ----
        #pragma unroll
        for (int st = 0; st < 4; ++st) {
            const int ao = aBase + st * 64;
            const short8 A0 = *(const short8*)(smem + ao);
            const short8 A1 = *(const short8*)(smem + A_SPL + ao);
            const short8 A2 = *(const short8*)(smem + 2 * A_SPL + ao);
            const int bo = bBase + st * 64;
            const short8 B00 = *(const short8*)(smem + bo);
            const short8 B01 = *(const short8*)(smem + bo + 16 * RSTR);
            const short8 B10 = *(const short8*)(smem + B_SPL + bo);
            const short8 B11 = *(const short8*)(smem + B_SPL + bo + 16 * RSTR);
            const short8 B20 = *(const short8*)(smem + 2 * B_SPL + bo);
            const short8 B21 = *(const short8*)(smem + 2 * B_SPL + bo + 16 * RSTR);
            acch0 = MFMA16(A0, B00, acch0);  acch1 = MFMA16(A0, B01, acch1);
            accl0 = MFMA16(A0, B10, accl0);  accl1 = MFMA16(A0, B11, accl1);
            accl0 = MFMA16(A1, B00, accl0);  accl1 = MFMA16(A1, B01, accl1);
            accl0 = MFMA16(A1, B10, accl0);  accl1 = MFMA16(A1, B11, accl1);
            accl0 = MFMA16(A0, B20, accl0);  accl1 = MFMA16(A0, B21, accl1);
            accl0 = MFMA16(A2, B00, accl0);  accl1 = MFMA16(A2, B01, accl1);
        }

        // ---- span dump: hi-term f32 acc -> f64, reset (keeps acc error ~4e-8)
        #pragma unroll
        for (int i = 0; i < 4; ++i) {
            accd0[i] += (double)acch0[i];
            accd1[i] += (double)acch1[i];
        }
        acch0 = z4; acch1 = z4;

        __syncthreads();            // all compute reads of the buffer done
        if (c + 1 < NCH) STAGE();   // split + write next chunk
        __syncthreads();            // staged data visible
    }

    // ---- epilogue: logits (f64 = hi-f64 + lo-f32) to global + LDS stash ----
    #pragma unroll
    for (int i = 0; i < 4; ++i) {
        const int trow = tw * 16 + rowmap[i];
        const int tok  = tok0 + trow;
        const int e0   = eh * 32 + colmap[i];
        const double l0 = accd0[i] + (double)accl0[i];
        const double l1 = accd1[i] + (double)accl1[i];
        out_logits[(size_t)tok * NE + e0]      = (float)l0;
        out_logits[(size_t)tok * NE + e0 + 16] = (float)l1;
        lg[trow][e0]      = l0;
        lg[trow][e0 + 16] = l1;
    }
    __syncthreads();

    // ---- per-token top-8 + renormalized softmax ----
    // Value-only f64 shuffle max; winner index recovered via ballot+ffs
    // (same tie-break: smallest index wins).
    for (int tt = wave; tt < TM; tt += 4) {
        double cur = lg[tt][lane];
        double first = 0.0;
        float  s = 0.f, myv = 0.f;
        int myi = 0;
        #pragma unroll
        for (int i = 0; i < TOPK; ++i) {
            double mv = cur;
            #pragma unroll
            for (int off = 32; off; off >>= 1) {
                const double ov = __shfl_xor(mv, off);
                mv = ov > mv ? ov : mv;
            }
            const unsigned long long m = __ballot(cur == mv);
            const int mi = __ffsll(m) - 1;
            if (i == 0) first = mv;
            const float e = expf((float)(mv - first));
            s += e;
            if (lane == i)  { myv = e; myi = mi; }
            if (lane == mi) cur = -INFINITY;   // remove winner
        }
        if (lane < TOPK) {
            const int tok = tok0 + tt;
            out_vals[(size_t)tok * TOPK + lane] = myv / s;
            out_idxf[(size_t)tok * TOPK + lane] = (float)myi;
        }
    }
}

extern "C" void kernel_launch(void* const* d_in, const int* in_sizes, int n_in,
                              void* d_out, int out_size, void* d_ws, size_t ws_size,
                              hipStream_t stream) {
    const float* hidden = (const float*)d_in[0];   // [16384, 2048] f32
    const float* weight = (const float*)d_in[1];   // [64, 2048] f32

    float* out        = (float*)d_out;
    float* out_logits = out;
    float* out_vals   = out + (size_t)T_TOKENS * NE;
    float* out_idxf   = out + (size_t)T_TOKENS * NE + (size_t)T_TOKENS * TOPK;

    dim3 grid(T_TOKENS / TM);
    dim3 block(256);
    hipLaunchKernelGGL(router_kernel, grid, block, 0, stream,
                       hidden, weight, out_logits, out_vals, out_idxf);
}

// Round 4
// 233.217 us; speedup vs baseline: 1.5461x; 1.0090x over previous
//
#include <hip/hip_runtime.h>
#include <math.h>

// Problem constants
#define T_TOKENS 16384
#define HID      2048
#define NE       64
#define TOPK     8
// Tiling
#define TM       32              // tokens per block -> grid 512 = 2 blocks/CU
#define BK       128             // k-chunk
#define NCH      (HID / BK)      // 16
// A LDS geometry: row = 128 bf16 + 8 pad = 272 B; 272/16 = 17 == 1 mod 8 ->
// every quarter-wave of a b128 frag read/write covers each 16B bank-group
// exactly 2x (free, m136).
#define RSTR     272
#define A_SPL    (32 * RSTR)     // 8704  : one A split plane
#define ABUF     (3 * A_SPL)     // 26112 : one buffer (3 planes)
#define LDS_BYTES (2 * ABUF)     // 52224 : double-buffered

// B fragment store in workspace (short8 = 16 B units):
//   idx = plane*16384 + kstep*256 + etile*64 + lane
// where lane holds W[etile*16 + (lane&15)][kstep*32 + (lane>>4)*8 .. +7]
// (identical mapping to R3's verified LDS frag reads).
#define WS_SHORT8 49152          // 3 * 64 * 4 * 64  -> 786432 B

typedef float  f32x4  __attribute__((ext_vector_type(4)));
typedef short  short8 __attribute__((ext_vector_type(8)));

#define MFMA16(A, B, C) __builtin_amdgcn_mfma_f32_16x16x32_bf16((A), (B), (C), 0, 0, 0)

// f32 <-> bf16 in pure bit ops (RNE)
static __device__ __forceinline__ unsigned short f2bf(float x) {
    unsigned u = __builtin_bit_cast(unsigned, x);
    return (unsigned short)((u + 0x7FFFu + ((u >> 16) & 1u)) >> 16);
}
static __device__ __forceinline__ float bf2f(unsigned short h) {
    unsigned u = ((unsigned)h) << 16;
    return __builtin_bit_cast(float, u);
}
// 3-term bf16 split: x ~= h0 + h1 + h2, |x - sum| <= 2^-27 |x|
static __device__ __forceinline__ void split1(float x, unsigned short& h0,
                                              unsigned short& h1, unsigned short& h2) {
    h0 = f2bf(x); float r = x - bf2f(h0);
    h1 = f2bf(r); r = r - bf2f(h1);
    h2 = f2bf(r);
}
#define SPLIT4(V, B, S0, S1, S2) do {                                             \
    unsigned short h0_, h1_, h2_;                                                 \
    split1((V).x, h0_, h1_, h2_); (S0)[(B)+0]=(short)h0_; (S1)[(B)+0]=(short)h1_; (S2)[(B)+0]=(short)h2_; \
    split1((V).y, h0_, h1_, h2_); (S0)[(B)+1]=(short)h0_; (S1)[(B)+1]=(short)h1_; (S2)[(B)+1]=(short)h2_; \
    split1((V).z, h0_, h1_, h2_); (S0)[(B)+2]=(short)h0_; (S1)[(B)+2]=(short)h1_; (S2)[(B)+2]=(short)h2_; \
    split1((V).w, h0_, h1_, h2_); (S0)[(B)+3]=(short)h0_; (S1)[(B)+3]=(short)h1_; (S2)[(B)+3]=(short)h2_; \
} while (0)

// ---- pre-pass: split weight once into 3 bf16 planes in B-frag layout ----
__global__ __launch_bounds__(256) void split_weight_kernel(
    const float* __restrict__ weight, short8* __restrict__ ws8)
{
    const int n = blockIdx.x;      // expert 0..63
    const int o = threadIdx.x;     // k-octet 0..255 (coalesced row read)
    const float4 w0 = *(const float4*)&weight[(size_t)n * HID + o * 8];
    const float4 w1 = *(const float4*)&weight[(size_t)n * HID + o * 8 + 4];
    short8 s0, s1, s2;
    SPLIT4(w0, 0, s0, s1, s2);
    SPLIT4(w1, 4, s0, s1, s2);
    const int t    = o >> 2;                   // k-step (K=32)
    const int lane = (o & 3) * 16 + (n & 15);  // frag lane
    const int e    = n >> 4;                   // expert tile
    const int base = t * 256 + e * 64 + lane;
    ws8[base]         = s0;
    ws8[base + 16384] = s1;
    ws8[base + 32768] = s2;
}

__global__ __launch_bounds__(256, 2) void router_kernel(
    const float* __restrict__ hidden,   // [T_TOKENS, HID] f32
    const short8* __restrict__ bfrag,   // pre-split B planes (frag layout)
    float* __restrict__ out_logits,     // [T_TOKENS, NE]
    float* __restrict__ out_vals,       // [T_TOKENS, TOPK]
    float* __restrict__ out_idxf)       // [T_TOKENS, TOPK] (indices as float)
{
    __shared__ __align__(16) char smem[LDS_BYTES];
    double (*lg)[NE + 1] = reinterpret_cast<double(*)[NE + 1]>(smem);

    const int tid  = threadIdx.x;
    const int tok0 = blockIdx.x * TM;
    const int lane = tid & 63;
    const int wave = tid >> 6;   // 0..3
    const int tw   = wave & 1;   // token sub-tile (16 tokens)
    const int eh   = wave >> 1;  // expert half (2 x 16-expert tiles)

    const int fr = lane & 15;    // frag row/col
    const int fk = lane >> 4;    // frag k-octet

    // ---- runtime D-layout probe (self-correcting; verified in R3) ----
    int rowmap[4], colmap[4];
    {
        const unsigned short mb = f2bf((float)fr);
        const unsigned short ob = f2bf(0.03125f);
        short8 vm, vo;
        #pragma unroll
        for (int j = 0; j < 8; ++j) { vm[j] = (short)mb; vo[j] = (short)ob; }
        const f32x4 z = {0.f, 0.f, 0.f, 0.f};
        const f32x4 pr = MFMA16(vm, vo, z);
        const f32x4 pc = MFMA16(vo, vm, z);
        #pragma unroll
        for (int i = 0; i < 4; ++i) {
            rowmap[i] = (int)(pr[i] + 0.5f);
            colmap[i] = (int)(pc[i] + 0.5f);
        }
    }

    // A staging map: 32 rows x 8 threads x 16 f32
    const int ar   = tid >> 3;
    const int ac16 = (tid & 7) * 16;
    const float* aG = hidden + (size_t)(tok0 + ar) * HID + ac16;
    const int aWOff = ar * RSTR + ac16 * 2;      // byte offset within a buffer

    // B frag pointer: loads at bP[t*256 + p*16384 (+64 for second etile)]
    const short8* bP = bfrag + eh * 128 + lane;

    // A frag read base (bytes within buffer)
    const int aOff = (tw * 16 + fr) * RSTR + fk * 16;

    const f32x4 z4 = {0.f, 0.f, 0.f, 0.f};
    f32x4 acch0 = z4, acch1 = z4;        // a0*b0 (dumped to f64 each chunk)
    f32x4 accl0 = z4, accl1 = z4;        // corrections (f32 over whole K)
    double accd0[4] = {0, 0, 0, 0}, accd1[4] = {0, 0, 0, 0};

    float4 pa[4];

    // ---- prologue: stage chunk 0 into buffer 0 ----
    {
        #pragma unroll
        for (int q = 0; q < 4; ++q) pa[q] = *(const float4*)(aG + 4 * q);
        short8 sa0a, sa0b, sa1a, sa1b, sa2a, sa2b;
        SPLIT4(pa[0], 0, sa0a, sa1a, sa2a); SPLIT4(pa[1], 4, sa0a, sa1a, sa2a);
        SPLIT4(pa[2], 0, sa0b, sa1b, sa2b); SPLIT4(pa[3], 4, sa0b, sa1b, sa2b);
        char* aW = smem + aWOff;
        *(short8*)(aW            ) = sa0a;  *(short8*)(aW             + 16) = sa0b;
        *(short8*)(aW +   A_SPL  ) = sa1a;  *(short8*)(aW +   A_SPL   + 16) = sa1b;
        *(short8*)(aW + 2*A_SPL  ) = sa2a;  *(short8*)(aW + 2*A_SPL   + 16) = sa2b;
    }
    __syncthreads();

    for (int c = 0; c < NCH; ++c) {
        const int cur = c & 1;
        const char* bufc = smem + cur * ABUF;

        // issue next chunk's A global loads first (latency hides under MFMA)
        if (c + 1 < NCH) {
            const int off = (c + 1) * BK;
            #pragma unroll
            for (int q = 0; q < 4; ++q) pa[q] = *(const float4*)(aG + off + 4 * q);
        }

        // ---- compute: 4 k-steps, A from LDS, B direct from L2 frag planes ----
        #pragma unroll
        for (int st = 0; st < 4; ++st) {
            const int t  = c * 4 + st;
            const int ao = aOff + st * 64;
            const short8 A0 = *(const short8*)(bufc + ao);
            const short8 A1 = *(const short8*)(bufc + A_SPL + ao);
            const short8 A2 = *(const short8*)(bufc + 2 * A_SPL + ao);
            const short8 B00 = bP[t * 256];
            const short8 B01 = bP[t * 256 + 64];
            const short8 B10 = bP[t * 256 + 16384];
            const short8 B11 = bP[t * 256 + 16384 + 64];
            const short8 B20 = bP[t * 256 + 32768];
            const short8 B21 = bP[t * 256 + 32768 + 64];
            acch0 = MFMA16(A0, B00, acch0);  acch1 = MFMA16(A0, B01, acch1);
            accl0 = MFMA16(A0, B10, accl0);  accl1 = MFMA16(A0, B11, accl1);
            accl0 = MFMA16(A1, B00, accl0);  accl1 = MFMA16(A1, B01, accl1);
            accl0 = MFMA16(A1, B10, accl0);  accl1 = MFMA16(A1, B11, accl1);
            accl0 = MFMA16(A0, B20, accl0);  accl1 = MFMA16(A0, B21, accl1);
            accl0 = MFMA16(A2, B00, accl0);  accl1 = MFMA16(A2, B01, accl1);
        }

        // ---- span dump: hi-term f32 acc -> f64, reset ----
        #pragma unroll
        for (int i = 0; i < 4; ++i) {
            accd0[i] += (double)acch0[i];
            accd1[i] += (double)acch1[i];
        }
        acch0 = z4; acch1 = z4;

        // ---- split + write next chunk into the other buffer, ONE barrier.
        // Writing buf[cur^1] here is safe: its last readers finished before
        // the barrier at the end of chunk c-1.
        if (c + 1 < NCH) {
            short8 sa0a, sa0b, sa1a, sa1b, sa2a, sa2b;
            SPLIT4(pa[0], 0, sa0a, sa1a, sa2a); SPLIT4(pa[1], 4, sa0a, sa1a, sa2a);
            SPLIT4(pa[2], 0, sa0b, sa1b, sa2b); SPLIT4(pa[3], 4, sa0b, sa1b, sa2b);
            char* aW = smem + (cur ^ 1) * ABUF + aWOff;
            *(short8*)(aW            ) = sa0a;  *(short8*)(aW             + 16) = sa0b;
            *(short8*)(aW +   A_SPL  ) = sa1a;  *(short8*)(aW +   A_SPL   + 16) = sa1b;
            *(short8*)(aW + 2*A_SPL  ) = sa2a;  *(short8*)(aW + 2*A_SPL   + 16) = sa2b;
        }
        // Barrier: staged writes visible before next chunk's reads; also orders
        // this chunk's reads of buf[cur] before chunk c+1's writes to it.
        __syncthreads();
    }

    // ---- epilogue: logits (f64 = hi-f64 + lo-f32) to global + LDS stash ----
    #pragma unroll
    for (int i = 0; i < 4; ++i) {
        const int trow = tw * 16 + rowmap[i];
        const int tok  = tok0 + trow;
        const int e0   = eh * 32 + colmap[i];
        const double l0 = accd0[i] + (double)accl0[i];
        const double l1 = accd1[i] + (double)accl1[i];
        out_logits[(size_t)tok * NE + e0]      = (float)l0;
        out_logits[(size_t)tok * NE + e0 + 16] = (float)l1;
        lg[trow][e0]      = l0;
        lg[trow][e0 + 16] = l1;
    }
    __syncthreads();

    // ---- per-token top-8 + renormalized softmax (verified in R3) ----
    for (int tt = wave; tt < TM; tt += 4) {
        double cur = lg[tt][lane];
        double first = 0.0;
        float  s = 0.f, myv = 0.f;
        int myi = 0;
        #pragma unroll
        for (int i = 0; i < TOPK; ++i) {
            double mv = cur;
            #pragma unroll
            for (int off = 32; off; off >>= 1) {
                const double ov = __shfl_xor(mv, off);
                mv = ov > mv ? ov : mv;
            }
            const unsigned long long m = __ballot(cur == mv);
            const int mi = __ffsll(m) - 1;
            if (i == 0) first = mv;
            const float e = expf((float)(mv - first));
            s += e;
            if (lane == i)  { myv = e; myi = mi; }
            if (lane == mi) cur = -INFINITY;   // remove winner
        }
        if (lane < TOPK) {
            const int tok = tok0 + tt;
            out_vals[(size_t)tok * TOPK + lane] = myv / s;
            out_idxf[(size_t)tok * TOPK + lane] = (float)myi;
        }
    }
}

extern "C" void kernel_launch(void* const* d_in, const int* in_sizes, int n_in,
                              void* d_out, int out_size, void* d_ws, size_t ws_size,
                              hipStream_t stream) {
    const float* hidden = (const float*)d_in[0];   // [16384, 2048] f32
    const float* weight = (const float*)d_in[1];   // [64, 2048] f32

    float* out        = (float*)d_out;
    float* out_logits = out;
    float* out_vals   = out + (size_t)T_TOKENS * NE;
    float* out_idxf   = out + (size_t)T_TOKENS * NE + (size_t)T_TOKENS * TOPK;

    short8* ws8 = (short8*)d_ws;   // needs 786432 B of workspace

    hipLaunchKernelGGL(split_weight_kernel, dim3(NE), dim3(256), 0, stream,
                       weight, ws8);
    hipLaunchKernelGGL(router_kernel, dim3(T_TOKENS / TM), dim3(256), 0, stream,
                       hidden, (const short8*)ws8, out_logits, out_vals, out_idxf);
}

// Round 5
// 229.884 us; speedup vs baseline: 1.5685x; 1.0145x over previous
//
#include <hip/hip_runtime.h>
#include <math.h>

// Problem constants
#define T_TOKENS 16384
#define HID      2048
#define NE       64
#define TOPK     8
// Tiling
#define TM       16              // tokens per block -> grid 1024 = 4 blocks/CU
#define BK       128             // k-chunk
#define NCH      (HID / BK)      // 16
// A LDS geometry: row = 128 bf16 + 8 pad = 272 B; 272/16 = 17 == 1 mod 8 ->
// b128 frag reads/writes cover all 16B bank-groups evenly (free, m136).
#define RSTR     272
#define A_SPL    (TM * RSTR)     // 4352  : one A split plane
#define ABUF     (3 * A_SPL)     // 13056 : one buffer (3 planes)
#define LDS_BYTES (2 * ABUF)     // 26112 : double-buffered -> 4 blocks/CU

// B fragment store in workspace (short8 = 16 B units):
//   idx = plane*16384 + kstep*256 + etile*64 + lane
// where lane holds W[etile*16 + (lane&15)][kstep*32 + (lane>>4)*8 .. +7]
#define WS_SHORT8 49152          // 3 * 64 * 4 * 64  -> 786432 B workspace

typedef float    f32x4  __attribute__((ext_vector_type(4)));
typedef short    short8 __attribute__((ext_vector_type(8)));
typedef unsigned uint4v __attribute__((ext_vector_type(4)));

#define MFMA16(A, B, C) __builtin_amdgcn_mfma_f32_16x16x32_bf16((A), (B), (C), 0, 0, 0)

// RNE f2bf (probe only; small ints exact either way)
static __device__ __forceinline__ unsigned short f2bf(float x) {
    unsigned u = __builtin_bit_cast(unsigned, x);
    return (unsigned short)((u + 0x7FFFu + ((u >> 16) & 1u)) >> 16);
}

// 3-plane bf16 split of 8 floats, packed as 3 x uint4 (short8 bit-identical).
// Plane rounding: round-half-away via (u+0x8000)&0xFFFF0000 — the masked word
// IS the plane value as f32 (no shifts on the compute path). Residual bound
// per level <= half-ulp (2^-8 rel), same as RNE; plane2 truncates (residual
// <= 2^-23 rel — dropped cross-terms ~2^-23|a||b|, negligible vs f32-seq 2e-6).
static __device__ __forceinline__ void split8(const float4 v0, const float4 v1,
                                              uint4v& p0, uint4v& p1, uint4v& p2)
{
    const float x[8] = {v0.x, v0.y, v0.z, v0.w, v1.x, v1.y, v1.z, v1.w};
    #pragma unroll
    for (int j = 0; j < 4; ++j) {
        const float xe = x[2 * j], xo = x[2 * j + 1];
        const unsigned ue  = __builtin_bit_cast(unsigned, xe);
        const unsigned m0e = (ue + 0x8000u) & 0xFFFF0000u;
        const float    r1e = xe - __builtin_bit_cast(float, m0e);
        const unsigned u1e = __builtin_bit_cast(unsigned, r1e);
        const unsigned m1e = (u1e + 0x8000u) & 0xFFFF0000u;
        const float    r2e = r1e - __builtin_bit_cast(float, m1e);
        const unsigned u2e = __builtin_bit_cast(unsigned, r2e);
        const unsigned uo  = __builtin_bit_cast(unsigned, xo);
        const unsigned m0o = (uo + 0x8000u) & 0xFFFF0000u;
        const float    r1o = xo - __builtin_bit_cast(float, m0o);
        const unsigned u1o = __builtin_bit_cast(unsigned, r1o);
        const unsigned m1o = (u1o + 0x8000u) & 0xFFFF0000u;
        const float    r2o = r1o - __builtin_bit_cast(float, m1o);
        const unsigned u2o = __builtin_bit_cast(unsigned, r2o);
        p0[j] = m0o | (m0e >> 16);
        p1[j] = m1o | (m1e >> 16);
        p2[j] = (u2o & 0xFFFF0000u) | (u2e >> 16);
    }
}

// ---- pre-pass: split weight once into 3 bf16 planes in B-frag layout ----
__global__ __launch_bounds__(256) void split_weight_kernel(
    const float* __restrict__ weight, uint4v* __restrict__ ws)
{
    const int n = blockIdx.x;      // expert 0..63
    const int o = threadIdx.x;     // k-octet 0..255 (coalesced row read)
    const float4 w0 = *(const float4*)&weight[(size_t)n * HID + o * 8];
    const float4 w1 = *(const float4*)&weight[(size_t)n * HID + o * 8 + 4];
    uint4v p0, p1, p2;
    split8(w0, w1, p0, p1, p2);
    const int t    = o >> 2;                   // k-step (K=32)
    const int lane = (o & 3) * 16 + (n & 15);  // frag lane
    const int e    = n >> 4;                   // expert tile
    const int base = t * 256 + e * 64 + lane;
    ws[base]         = p0;
    ws[base + 16384] = p1;
    ws[base + 32768] = p2;
}

__global__ __launch_bounds__(256, 4) void router_kernel(
    const float* __restrict__ hidden,   // [T_TOKENS, HID] f32
    const short8* __restrict__ bfrag,   // pre-split B planes (frag layout)
    float* __restrict__ out_logits,     // [T_TOKENS, NE]
    float* __restrict__ out_vals,       // [T_TOKENS, TOPK]
    float* __restrict__ out_idxf)       // [T_TOKENS, TOPK] (indices as float)
{
    __shared__ __align__(16) char smem[LDS_BYTES];
    double (*lg)[NE + 1] = reinterpret_cast<double(*)[NE + 1]>(smem);

    const int tid  = threadIdx.x;
    const int tok0 = blockIdx.x * TM;
    const int lane = tid & 63;
    const int wave = tid >> 6;   // 0..3 == expert tile of this wave

    const int fr = lane & 15;    // frag row/col
    const int fk = lane >> 4;    // frag k-octet

    // ---- runtime D-layout probe (self-correcting; verified R3/R4) ----
    int rowmap[4], colmap[4];
    {
        const unsigned short mb = f2bf((float)fr);
        const unsigned short ob = f2bf(0.03125f);
        short8 vm, vo;
        #pragma unroll
        for (int j = 0; j < 8; ++j) { vm[j] = (short)mb; vo[j] = (short)ob; }
        const f32x4 z = {0.f, 0.f, 0.f, 0.f};
        const f32x4 pr = MFMA16(vm, vo, z);
        const f32x4 pc = MFMA16(vo, vm, z);
        #pragma unroll
        for (int i = 0; i < 4; ++i) {
            rowmap[i] = (int)(pr[i] + 0.5f);
            colmap[i] = (int)(pc[i] + 0.5f);
        }
    }

    // A staging map: 16 rows x 16 threads x 8 f32 (512 B coalesced per row)
    const int ar  = tid >> 4;
    const int ac8 = (tid & 15) * 8;
    const float* aG = hidden + (size_t)(tok0 + ar) * HID + ac8;
    const int aWOff = ar * RSTR + ac8 * 2;       // byte offset within a buffer

    // B frag pointer: this wave's expert tile; loads at bP[t*256 + plane*16384]
    const short8* bP = bfrag + wave * 64 + lane;

    // A frag read base (bytes within buffer)
    const int aOff = fr * RSTR + fk * 16;

    const f32x4 z4 = {0.f, 0.f, 0.f, 0.f};
    f32x4 acch = z4;                     // a0*b0 (dumped to f64 each chunk)
    f32x4 accl = z4;                     // 5 correction terms (f32 whole K)
    double accd[4] = {0, 0, 0, 0};

    float4 pa0, pa1;

    // ---- prologue: stage chunk 0 into buffer 0 ----
    {
        pa0 = *(const float4*)(aG);
        pa1 = *(const float4*)(aG + 4);
        uint4v p0, p1, p2;
        split8(pa0, pa1, p0, p1, p2);
        char* aW = smem + aWOff;
        *(uint4v*)(aW            ) = p0;
        *(uint4v*)(aW +   A_SPL  ) = p1;
        *(uint4v*)(aW + 2*A_SPL  ) = p2;
    }
    __syncthreads();

    for (int c = 0; c < NCH; ++c) {
        const int cur = c & 1;
        const char* bufc = smem + cur * ABUF;

        // T14: issue next chunk's A global loads first (hide under MFMA)
        if (c + 1 < NCH) {
            const int off = (c + 1) * BK;
            pa0 = *(const float4*)(aG + off);
            pa1 = *(const float4*)(aG + off + 4);
        }

        // ---- compute: 4 k-steps; A from LDS, B direct from L2 frag planes ----
        #pragma unroll
        for (int st = 0; st < 4; ++st) {
            const int t  = c * 4 + st;
            const int ao = aOff + st * 64;
            const short8 A0 = *(const short8*)(bufc + ao);
            const short8 A1 = *(const short8*)(bufc + A_SPL + ao);
            const short8 A2 = *(const short8*)(bufc + 2 * A_SPL + ao);
            const short8 B0 = bP[t * 256];
            const short8 B1 = bP[t * 256 + 16384];
            const short8 B2 = bP[t * 256 + 32768];
            acch = MFMA16(A0, B0, acch);
            accl = MFMA16(A0, B1, accl);
            accl = MFMA16(A1, B0, accl);
            accl = MFMA16(A1, B1, accl);
            accl = MFMA16(A0, B2, accl);
            accl = MFMA16(A2, B0, accl);
        }

        // ---- span dump: hi-term f32 acc -> f64, reset ----
        #pragma unroll
        for (int i = 0; i < 4; ++i) accd[i] += (double)acch[i];
        acch = z4;

        // ---- split + write next chunk into the other buffer, ONE barrier.
        // buf[cur^1]'s last readers finished before the barrier ending c-1.
        if (c + 1 < NCH) {
            uint4v p0, p1, p2;
            split8(pa0, pa1, p0, p1, p2);
            char* aW = smem + (cur ^ 1) * ABUF + aWOff;
            *(uint4v*)(aW            ) = p0;
            *(uint4v*)(aW +   A_SPL  ) = p1;
            *(uint4v*)(aW + 2*A_SPL  ) = p2;
        }
        __syncthreads();
    }

    // ---- epilogue: logits (f64 = hi-f64 + lo-f32) to global + LDS stash ----
    #pragma unroll
    for (int i = 0; i < 4; ++i) {
        const int trow = rowmap[i];
        const int tok  = tok0 + trow;
        const int e0   = wave * 16 + colmap[i];
        const double l0 = accd[i] + (double)accl[i];
        out_logits[(size_t)tok * NE + e0] = (float)l0;
        lg[trow][e0] = l0;
    }
    __syncthreads();

    // ---- per-token top-8 + renormalized softmax (verified R3/R4) ----
    for (int tt = wave; tt < TM; tt += 4) {
        double cur = lg[tt][lane];
        double first = 0.0;
        float  s = 0.f, myv = 0.f;
        int myi = 0;
        #pragma unroll
        for (int i = 0; i < TOPK; ++i) {
            double mv = cur;
            #pragma unroll
            for (int off = 32; off; off >>= 1) {
                const double ov = __shfl_xor(mv, off);
                mv = ov > mv ? ov : mv;
            }
            const unsigned long long m = __ballot(cur == mv);
            const int mi = __ffsll(m) - 1;
            if (i == 0) first = mv;
            const float e = expf((float)(mv - first));
            s += e;
            if (lane == i)  { myv = e; myi = mi; }
            if (lane == mi) cur = -INFINITY;   // remove winner
        }
        if (lane < TOPK) {
            const int tok = tok0 + tt;
            out_vals[(size_t)tok * TOPK + lane] = myv / s;
            out_idxf[(size_t)tok * TOPK + lane] = (float)myi;
        }
    }
}

extern "C" void kernel_launch(void* const* d_in, const int* in_sizes, int n_in,
                              void* d_out, int out_size, void* d_ws, size_t ws_size,
                              hipStream_t stream) {
    const float* hidden = (const float*)d_in[0];   // [16384, 2048] f32
    const float* weight = (const float*)d_in[1];   // [64, 2048] f32

    float* out        = (float*)d_out;
    float* out_logits = out;
    float* out_vals   = out + (size_t)T_TOKENS * NE;
    float* out_idxf   = out + (size_t)T_TOKENS * NE + (size_t)T_TOKENS * TOPK;

    uint4v* ws = (uint4v*)d_ws;   // needs 786432 B of workspace

    hipLaunchKernelGGL(split_weight_kernel, dim3(NE), dim3(256), 0, stream,
                       weight, ws);
    hipLaunchKernelGGL(router_kernel, dim3(T_TOKENS / TM), dim3(256), 0, stream,
                       hidden, (const short8*)ws, out_logits, out_vals, out_idxf);
}

// Round 6
// 221.411 us; speedup vs baseline: 1.6285x; 1.0383x over previous
//
#include <hip/hip_runtime.h>
#include <math.h>

// Problem constants
#define T_TOKENS 16384
#define HID      2048
#define NE       64
#define TOPK     8
// Tiling
#define TM       32              // tokens per block -> grid 512 = 2 blocks/CU
#define BK       128             // k-chunk
#define NCH      (HID / BK)      // 16
// A LDS geometry: row = 128 bf16 + 8 pad = 272 B; 272 mod 128 = 16 ->
// b128 frag reads hit each 16B bank-group exactly 2x per quarter-wave (free).
#define RSTR     272
#define A_SPL    (TM * RSTR)     // 8704  : one A split plane
#define ABUF     (3 * A_SPL)     // 26112 : one buffer (3 planes)
#define LDS_BYTES (2 * ABUF)     // 52224 : double-buffered -> 2 blocks/CU

// B fragment store in workspace (short8 = 16 B units):
//   idx = plane*16384 + kstep*256 + etile*64 + lane
// lane holds W[etile*16 + (lane&15)][kstep*32 + (lane>>4)*8 .. +7]
#define WS_SHORT8 49152          // 786432 B workspace

typedef float    f32x4  __attribute__((ext_vector_type(4)));
typedef short    short8 __attribute__((ext_vector_type(8)));
typedef unsigned uint4v __attribute__((ext_vector_type(4)));

#define MFMA16(A, B, C) __builtin_amdgcn_mfma_f32_16x16x32_bf16((A), (B), (C), 0, 0, 0)

// RNE f2bf (probe only)
static __device__ __forceinline__ unsigned short f2bf(float x) {
    unsigned u = __builtin_bit_cast(unsigned, x);
    return (unsigned short)((u + 0x7FFFu + ((u >> 16) & 1u)) >> 16);
}

// 3-plane bf16 split of 8 floats, packed as 3 x uint4 (bit-identical to R4/R5).
static __device__ __forceinline__ void split8(const float4 v0, const float4 v1,
                                              uint4v& p0, uint4v& p1, uint4v& p2)
{
    const float x[8] = {v0.x, v0.y, v0.z, v0.w, v1.x, v1.y, v1.z, v1.w};
    #pragma unroll
    for (int j = 0; j < 4; ++j) {
        const float xe = x[2 * j], xo = x[2 * j + 1];
        const unsigned ue  = __builtin_bit_cast(unsigned, xe);
        const unsigned m0e = (ue + 0x8000u) & 0xFFFF0000u;
        const float    r1e = xe - __builtin_bit_cast(float, m0e);
        const unsigned u1e = __builtin_bit_cast(unsigned, r1e);
        const unsigned m1e = (u1e + 0x8000u) & 0xFFFF0000u;
        const float    r2e = r1e - __builtin_bit_cast(float, m1e);
        const unsigned u2e = __builtin_bit_cast(unsigned, r2e);
        const unsigned uo  = __builtin_bit_cast(unsigned, xo);
        const unsigned m0o = (uo + 0x8000u) & 0xFFFF0000u;
        const float    r1o = xo - __builtin_bit_cast(float, m0o);
        const unsigned u1o = __builtin_bit_cast(unsigned, r1o);
        const unsigned m1o = (u1o + 0x8000u) & 0xFFFF0000u;
        const float    r2o = r1o - __builtin_bit_cast(float, m1o);
        const unsigned u2o = __builtin_bit_cast(unsigned, r2o);
        p0[j] = m0o | (m0e >> 16);
        p1[j] = m1o | (m1e >> 16);
        p2[j] = (u2o & 0xFFFF0000u) | (u2e >> 16);
    }
}

// ---- pre-pass: split weight once into 3 bf16 planes in B-frag layout ----
__global__ __launch_bounds__(256) void split_weight_kernel(
    const float* __restrict__ weight, uint4v* __restrict__ ws)
{
    const int n = blockIdx.x;      // expert 0..63
    const int o = threadIdx.x;     // k-octet 0..255
    const float4 w0 = *(const float4*)&weight[(size_t)n * HID + o * 8];
    const float4 w1 = *(const float4*)&weight[(size_t)n * HID + o * 8 + 4];
    uint4v p0, p1, p2;
    split8(w0, w1, p0, p1, p2);
    const int t    = o >> 2;
    const int lane = (o & 3) * 16 + (n & 15);
    const int e    = n >> 4;
    const int base = t * 256 + e * 64 + lane;
    ws[base]         = p0;
    ws[base + 16384] = p1;
    ws[base + 32768] = p2;
}

__global__ __launch_bounds__(256, 2) void router_kernel(
    const float* __restrict__ hidden,   // [T_TOKENS, HID] f32
    const short8* __restrict__ bfrag,   // pre-split B planes (frag layout)
    float* __restrict__ out_logits,     // [T_TOKENS, NE]
    float* __restrict__ out_vals,       // [T_TOKENS, TOPK]
    float* __restrict__ out_idxf)       // [T_TOKENS, TOPK]
{
    __shared__ __align__(16) char smem[LDS_BYTES];
    double (*lg)[NE + 1] = reinterpret_cast<double(*)[NE + 1]>(smem);

    const int tid  = threadIdx.x;
    const int tok0 = blockIdx.x * TM;
    const int lane = tid & 63;
    const int wave = tid >> 6;   // 0..3 == expert tile of this wave

    const int fr = lane & 15;
    const int fk = lane >> 4;

    // ---- runtime D-layout probe (verified R3-R5) ----
    int rowmap[4], colmap[4];
    {
        const unsigned short mb = f2bf((float)fr);
        const unsigned short ob = f2bf(0.03125f);
        short8 vm, vo;
        #pragma unroll
        for (int j = 0; j < 8; ++j) { vm[j] = (short)mb; vo[j] = (short)ob; }
        const f32x4 z = {0.f, 0.f, 0.f, 0.f};
        const f32x4 pr = MFMA16(vm, vo, z);
        const f32x4 pc = MFMA16(vo, vm, z);
        #pragma unroll
        for (int i = 0; i < 4; ++i) {
            rowmap[i] = (int)(pr[i] + 0.5f);
            colmap[i] = (int)(pc[i] + 0.5f);
        }
    }

    // A staging map: 32 rows x 8 threads x 16 f32 (512 B coalesced per row)
    const int ar   = tid >> 3;
    const int ac16 = (tid & 7) * 16;
    const float* aG = hidden + (size_t)(tok0 + ar) * HID + ac16;
    const int aWOff = ar * RSTR + ac16 * 2;      // bytes within a buffer

    // B frag pointer: this wave's expert tile
    const short8* bP = bfrag + wave * 64 + lane;

    // A frag read bases (bytes within buffer) for the 2 token-frags
    const int aOff0 = fr * RSTR + fk * 16;
    const int aOff1 = (16 + fr) * RSTR + fk * 16;

    const f32x4 z4 = {0.f, 0.f, 0.f, 0.f};
    f32x4 acch[2] = {z4, z4};            // a0*b0 per token-frag
    f32x4 accl[2] = {z4, z4};            // corrections per token-frag
    double accd[2][4] = {{0, 0, 0, 0}, {0, 0, 0, 0}};

    float4 pa[4];
    short8 Bcur0, Bcur1, Bcur2;          // B planes, current k-step

    // ---- prologue: stage chunk 0 + preload B(t=0) ----
    {
        #pragma unroll
        for (int q = 0; q < 4; ++q) pa[q] = *(const float4*)(aG + 4 * q);
        uint4v p0, p1, p2;
        char* aW = smem + aWOff;
        split8(pa[0], pa[1], p0, p1, p2);
        *(uint4v*)(aW            ) = p0;
        *(uint4v*)(aW +   A_SPL  ) = p1;
        *(uint4v*)(aW + 2*A_SPL  ) = p2;
        split8(pa[2], pa[3], p0, p1, p2);
        *(uint4v*)(aW             + 16) = p0;
        *(uint4v*)(aW +   A_SPL   + 16) = p1;
        *(uint4v*)(aW + 2*A_SPL   + 16) = p2;
    }
    Bcur0 = bP[0];
    Bcur1 = bP[16384];
    Bcur2 = bP[32768];
    __syncthreads();

    for (int c = 0; c < NCH; ++c) {
        const char* bufc = smem + (c & 1) * ABUF;

        // A frags for st=0 (ds latency exposed once per chunk)
        short8 A00 = *(const short8*)(bufc + aOff0);
        short8 A01 = *(const short8*)(bufc + A_SPL + aOff0);
        short8 A02 = *(const short8*)(bufc + 2 * A_SPL + aOff0);
        short8 A10 = *(const short8*)(bufc + aOff1);
        short8 A11 = *(const short8*)(bufc + A_SPL + aOff1);
        short8 A12 = *(const short8*)(bufc + 2 * A_SPL + aOff1);

        // T14: issue next chunk's A global loads (hide under MFMA phase)
        if (c + 1 < NCH) {
            const int off = (c + 1) * BK;
            #pragma unroll
            for (int q = 0; q < 4; ++q) pa[q] = *(const float4*)(aG + off + 4 * q);
        }

        // ---- 4 k-steps, explicit 1-step pipeline ----
        #pragma unroll
        for (int st = 0; st < 4; ++st) {
            // prefetch next step's operands (or next chunk's first B across
            // the barrier — B has no LDS dependency)
            short8 An00, An01, An02, An10, An11, An12;
            short8 Bn0, Bn1, Bn2;
            if (st < 3) {
                const int ao = (st + 1) * 64;
                An00 = *(const short8*)(bufc + aOff0 + ao);
                An01 = *(const short8*)(bufc + A_SPL + aOff0 + ao);
                An02 = *(const short8*)(bufc + 2 * A_SPL + aOff0 + ao);
                An10 = *(const short8*)(bufc + aOff1 + ao);
                An11 = *(const short8*)(bufc + A_SPL + aOff1 + ao);
                An12 = *(const short8*)(bufc + 2 * A_SPL + aOff1 + ao);
                const int t = c * 4 + st + 1;
                Bn0 = bP[t * 256];
                Bn1 = bP[t * 256 + 16384];
                Bn2 = bP[t * 256 + 32768];
            } else if (c + 1 < NCH) {
                const int t = (c + 1) * 4;
                Bn0 = bP[t * 256];
                Bn1 = bP[t * 256 + 16384];
                Bn2 = bP[t * 256 + 32768];
            }

            // 12 MFMAs on current regs (4 per B-load)
            acch[0] = MFMA16(A00, Bcur0, acch[0]);
            accl[0] = MFMA16(A00, Bcur1, accl[0]);
            accl[0] = MFMA16(A01, Bcur0, accl[0]);
            accl[0] = MFMA16(A01, Bcur1, accl[0]);
            accl[0] = MFMA16(A00, Bcur2, accl[0]);
            accl[0] = MFMA16(A02, Bcur0, accl[0]);
            acch[1] = MFMA16(A10, Bcur0, acch[1]);
            accl[1] = MFMA16(A10, Bcur1, accl[1]);
            accl[1] = MFMA16(A11, Bcur0, accl[1]);
            accl[1] = MFMA16(A11, Bcur1, accl[1]);
            accl[1] = MFMA16(A10, Bcur2, accl[1]);
            accl[1] = MFMA16(A12, Bcur0, accl[1]);

            if (st < 3) {
                A00 = An00; A01 = An01; A02 = An02;
                A10 = An10; A11 = An11; A12 = An12;
                Bcur0 = Bn0; Bcur1 = Bn1; Bcur2 = Bn2;
            } else if (c + 1 < NCH) {
                Bcur0 = Bn0; Bcur1 = Bn1; Bcur2 = Bn2;
            }
        }

        // ---- span dump: hi-term f32 acc -> f64, reset ----
        #pragma unroll
        for (int f = 0; f < 2; ++f) {
            #pragma unroll
            for (int i = 0; i < 4; ++i) accd[f][i] += (double)acch[f][i];
            acch[f] = z4;
        }

        // ---- split + write next chunk into the other buffer, ONE barrier ----
        if (c + 1 < NCH) {
            uint4v p0, p1, p2;
            char* aW = smem + ((c & 1) ^ 1) * ABUF + aWOff;
            split8(pa[0], pa[1], p0, p1, p2);
            *(uint4v*)(aW            ) = p0;
            *(uint4v*)(aW +   A_SPL  ) = p1;
            *(uint4v*)(aW + 2*A_SPL  ) = p2;
            split8(pa[2], pa[3], p0, p1, p2);
            *(uint4v*)(aW             + 16) = p0;
            *(uint4v*)(aW +   A_SPL   + 16) = p1;
            *(uint4v*)(aW + 2*A_SPL   + 16) = p2;
        }
        __syncthreads();
    }

    // ---- epilogue: logits (f64 = hi-f64 + lo-f32) to global + LDS stash ----
    #pragma unroll
    for (int f = 0; f < 2; ++f) {
        #pragma unroll
        for (int i = 0; i < 4; ++i) {
            const int trow = f * 16 + rowmap[i];
            const int tok  = tok0 + trow;
            const int e0   = wave * 16 + colmap[i];
            const double l0 = accd[f][i] + (double)accl[f][i];
            out_logits[(size_t)tok * NE + e0] = (float)l0;
            lg[trow][e0] = l0;
        }
    }
    __syncthreads();

    // ---- per-token top-8 + renormalized softmax (verified R3-R5) ----
    for (int tt = wave; tt < TM; tt += 4) {
        double cur = lg[tt][lane];
        double first = 0.0;
        float  s = 0.f, myv = 0.f;
        int myi = 0;
        #pragma unroll
        for (int i = 0; i < TOPK; ++i) {
            double mv = cur;
            #pragma unroll
            for (int off = 32; off; off >>= 1) {
                const double ov = __shfl_xor(mv, off);
                mv = ov > mv ? ov : mv;
            }
            const unsigned long long m = __ballot(cur == mv);
            const int mi = __ffsll(m) - 1;
            if (i == 0) first = mv;
            const float e = expf((float)(mv - first));
            s += e;
            if (lane == i)  { myv = e; myi = mi; }
            if (lane == mi) cur = -INFINITY;
        }
        if (lane < TOPK) {
            const int tok = tok0 + tt;
            out_vals[(size_t)tok * TOPK + lane] = myv / s;
            out_idxf[(size_t)tok * TOPK + lane] = (float)myi;
        }
    }
}

extern "C" void kernel_launch(void* const* d_in, const int* in_sizes, int n_in,
                              void* d_out, int out_size, void* d_ws, size_t ws_size,
                              hipStream_t stream) {
    const float* hidden = (const float*)d_in[0];   // [16384, 2048] f32
    const float* weight = (const float*)d_in[1];   // [64, 2048] f32

    float* out        = (float*)d_out;
    float* out_logits = out;
    float* out_vals   = out + (size_t)T_TOKENS * NE;
    float* out_idxf   = out + (size_t)T_TOKENS * NE + (size_t)T_TOKENS * TOPK;

    uint4v* ws = (uint4v*)d_ws;   // needs 786432 B of workspace

    hipLaunchKernelGGL(split_weight_kernel, dim3(NE), dim3(256), 0, stream,
                       weight, ws);
    hipLaunchKernelGGL(router_kernel, dim3(T_TOKENS / TM), dim3(256), 0, stream,
                       hidden, (const short8*)ws, out_logits, out_vals, out_idxf);
}